// Round 1
// baseline (3320.370 us; speedup 1.0000x reference)
//
#include <hip/hip_runtime.h>

// LSTM decoder: NLAYERS=4, NHID=1024, NOUT=512, BSZ=64, STEPS=128
// Wavefront schedule: (layer l, scan-step s) runs at wave w = s + l.
// 131 waves, each one kernel launch (graph-captured). Gate GEMM (K=2048:
// U-part on old h[l], W-part on new hy[l-1]) fused with LSTM cell epilogue.
// bf16 MFMA 16x16x32, f32 accum; c state f32; h state bf16 ping-pong.

#define H     1024
#define B     64
#define G4    4096
#define NL    4
#define NOUTD 512
#define NSCAN 127
#define NWAVES 131

typedef __attribute__((ext_vector_type(8))) short short8;
typedef __attribute__((ext_vector_type(4))) float f32x4;

__device__ __forceinline__ unsigned short f2bf(float x) {
  union { float f; unsigned int u; } v; v.f = x;
  unsigned int r = v.u + 0x7FFFu + ((v.u >> 16) & 1u);
  return (unsigned short)(r >> 16);
}
__device__ __forceinline__ float sigmoidf_(float x) {
  return 1.0f / (1.0f + __expf(-x));
}
__device__ __forceinline__ float tanhf_(float x) {
  float ax = fabsf(x);
  float t = __expf(-2.0f * ax);
  float r = 1.0f - 2.0f * t / (1.0f + t);
  return copysignf(r, x);
}

// ---------------- prologue: f32 -> bf16 weight/state conversion ----------------
__global__ void prep_kernel(const float* __restrict__ hx, const float* __restrict__ cx,
                            const float* __restrict__ Wm, const float* __restrict__ Um,
                            const float* __restrict__ Lm,
                            unsigned short* __restrict__ Ubf, unsigned short* __restrict__ Wbf,
                            unsigned short* __restrict__ Lbf, unsigned short* __restrict__ hbf,
                            float* __restrict__ c) {
  const int tid = blockIdx.x * blockDim.x + threadIdx.x;
  const int nth = gridDim.x * blockDim.x;
  for (int i = tid; i < (NL * G4 * H) / 4; i += nth) {
    float4 v = ((const float4*)Um)[i];
    ushort4 o; o.x = f2bf(v.x); o.y = f2bf(v.y); o.z = f2bf(v.z); o.w = f2bf(v.w);
    ((ushort4*)Ubf)[i] = o;
  }
  for (int i = tid; i < (3 * G4 * H) / 4; i += nth) {
    float4 v = ((const float4*)Wm)[i];
    ushort4 o; o.x = f2bf(v.x); o.y = f2bf(v.y); o.z = f2bf(v.z); o.w = f2bf(v.w);
    ((ushort4*)Wbf)[i] = o;
  }
  for (int i = tid; i < (NOUTD * H) / 4; i += nth) {
    float4 v = ((const float4*)Lm)[i];
    ushort4 o; o.x = f2bf(v.x); o.y = f2bf(v.y); o.z = f2bf(v.z); o.w = f2bf(v.w);
    ((ushort4*)Lbf)[i] = o;
  }
  for (int i = tid; i < (NL * B * H) / 4; i += nth) {
    float4 v = ((const float4*)hx)[i];
    ushort4 o; o.x = f2bf(v.x); o.y = f2bf(v.y); o.z = f2bf(v.z); o.w = f2bf(v.w);
    ((ushort4*)hbf)[i] = o;                         // buffer 0
    ((ushort4*)(hbf + NL * B * H))[i] = o;          // buffer 1
  }
  for (int i = tid; i < (NL * B * H) / 4; i += nth) {
    ((float4*)c)[i] = ((const float4*)cx)[i];
  }
}

// ---------------- per-wave kernel ----------------
// blocks 0..255: gate+cell blocks. l = bid>>6, jt = bid&63 (16 hidden cols).
//   wave wv (0..3) owns gate chunk wv (i/f/g/o) for those 16 cols.
// blocks 256..263: output projection out[t] = h3 @ L^T, 64 cols per block.
__global__ __launch_bounds__(256) void wave_kernel(
    int w,
    const unsigned short* __restrict__ Ubf, const unsigned short* __restrict__ Wbf,
    const unsigned short* __restrict__ Lbf,
    unsigned short* __restrict__ hbf, float* __restrict__ c, float* __restrict__ out) {
  __shared__ __align__(16) unsigned short As[64 * 136];  // A tile [64][128] + pad 8
  __shared__ float Gs[4 * 64 * 16];                      // gates [chunk][b][jj] f32

  const int tid  = threadIdx.x;
  const int wv   = tid >> 6;
  const int lane = tid & 63;
  const int l15  = lane & 15;
  const int lhi  = lane >> 4;
  const int rd   = (w + 1) & 1;
  const int wr   = w & 1;
  const unsigned short* hrd = hbf + (size_t)rd * (NL * B * H);

  if (blockIdx.x < 256) {
    const int l  = blockIdx.x >> 6;
    const int jt = blockIdx.x & 63;
    const int s  = w - l;
    if (s < 0 || s >= NSCAN) return;

    const unsigned short* A1 = hrd + (size_t)l * B * H;
    const unsigned short* A2 = (l > 0) ? (hrd + (size_t)(l - 1) * B * H) : nullptr;
    const int r0 = wv * H + jt * 16;  // this wave's gate-row base (chunk = wv)
    const unsigned short* Bu = Ubf + ((size_t)l * G4 + r0 + l15) * H;
    const unsigned short* Bw = (l > 0) ? (Wbf + ((size_t)(l - 1) * G4 + r0 + l15) * H) : nullptr;

    f32x4 acc[4];
#pragma unroll
    for (int m = 0; m < 4; ++m) acc[m] = (f32x4){0.f, 0.f, 0.f, 0.f};

    for (int part = 0; part < 2; ++part) {
      if (part == 1 && l == 0) break;
      const unsigned short* Ap = part ? A2 : A1;
      const unsigned short* Bp = part ? Bw : Bu;
      for (int kb = 0; kb < 8; ++kb) {
        __syncthreads();
#pragma unroll
        for (int i = 0; i < 4; ++i) {
          int g = tid + 256 * i;
          int row = g >> 4, cu = g & 15;
          *(short8*)(&As[row * 136 + cu * 8]) =
              *(const short8*)(&Ap[(size_t)row * H + kb * 128 + cu * 8]);
        }
        __syncthreads();
#pragma unroll
        for (int kk = 0; kk < 4; ++kk) {
          const int ko = kk * 32 + 8 * lhi;
          short8 bfrag = *(const short8*)(&Bp[kb * 128 + ko]);
#pragma unroll
          for (int m = 0; m < 4; ++m) {
            short8 afrag = *(const short8*)(&As[(m * 16 + l15) * 136 + ko]);
            acc[m] = __builtin_amdgcn_mfma_f32_16x16x32_bf16(afrag, bfrag, acc[m], 0, 0, 0);
          }
        }
      }
    }

    // D layout (m89-verified): row = (lane>>4)*4 + reg, col = lane&15
    __syncthreads();
#pragma unroll
    for (int m = 0; m < 4; ++m)
#pragma unroll
      for (int j = 0; j < 4; ++j) {
        int b = m * 16 + lhi * 4 + j;
        Gs[wv * 1024 + b * 16 + l15] = acc[m][j];
      }
    __syncthreads();

    // fused LSTM cell: 4 elements per thread
    {
      int e = tid * 4;
      int b = e >> 4;
      int jj = e & 15;
      float* cp = c + ((size_t)l * B + b) * H + jt * 16 + jj;
      unsigned short* hp = hbf + (size_t)wr * (NL * B * H) + ((size_t)l * B + b) * H + jt * 16 + jj;
      float4 cold = *(float4*)cp;
      float4 cy;
      ushort4 hy;
      float cov[4] = {cold.x, cold.y, cold.z, cold.w};
      float cyv[4];
      unsigned short hyv[4];
#pragma unroll
      for (int q = 0; q < 4; ++q) {
        float ig = Gs[0 * 1024 + b * 16 + jj + q];
        float fg = Gs[1 * 1024 + b * 16 + jj + q];
        float gg = Gs[2 * 1024 + b * 16 + jj + q];
        float og = Gs[3 * 1024 + b * 16 + jj + q];
        float i_ = sigmoidf_(ig);
        float f_ = sigmoidf_(fg);
        float g_ = tanhf_(gg);
        float o_ = sigmoidf_(og);
        float cv = f_ * cov[q] + i_ * g_;
        cyv[q] = cv;
        hyv[q] = f2bf(o_ * tanhf_(cv));
      }
      cy.x = cyv[0]; cy.y = cyv[1]; cy.z = cyv[2]; cy.w = cyv[3];
      hy.x = hyv[0]; hy.y = hyv[1]; hy.z = hyv[2]; hy.w = hyv[3];
      *(float4*)cp = cy;
      *(ushort4*)hp = hy;
    }
  } else {
    // ---- projection block ----
    if (!(w == 0 || (w >= 4 && w <= 130))) return;
    const int pid = blockIdx.x - 256;         // 0..7
    const int t_out = (w == 0) ? 0 : (w - 3); // 0..127
    const unsigned short* A1 = hrd + (size_t)3 * B * H;
    const int r0 = pid * 64 + wv * 16;
    const unsigned short* Bp = Lbf + (size_t)(r0 + l15) * H;

    f32x4 acc[4];
#pragma unroll
    for (int m = 0; m < 4; ++m) acc[m] = (f32x4){0.f, 0.f, 0.f, 0.f};

    for (int kb = 0; kb < 8; ++kb) {
      __syncthreads();
#pragma unroll
      for (int i = 0; i < 4; ++i) {
        int g = tid + 256 * i;
        int row = g >> 4, cu = g & 15;
        *(short8*)(&As[row * 136 + cu * 8]) =
            *(const short8*)(&A1[(size_t)row * H + kb * 128 + cu * 8]);
      }
      __syncthreads();
#pragma unroll
      for (int kk = 0; kk < 4; ++kk) {
        const int ko = kk * 32 + 8 * lhi;
        short8 bfrag = *(const short8*)(&Bp[kb * 128 + ko]);
#pragma unroll
        for (int m = 0; m < 4; ++m) {
          short8 afrag = *(const short8*)(&As[(m * 16 + l15) * 136 + ko]);
          acc[m] = __builtin_amdgcn_mfma_f32_16x16x32_bf16(afrag, bfrag, acc[m], 0, 0, 0);
        }
      }
    }
    float* op = out + (size_t)t_out * B * NOUTD;
#pragma unroll
    for (int m = 0; m < 4; ++m)
#pragma unroll
      for (int j = 0; j < 4; ++j) {
        int b = m * 16 + lhi * 4 + j;
        op[(size_t)b * NOUTD + r0 + l15] = acc[m][j];
      }
  }
}

extern "C" void kernel_launch(void* const* d_in, const int* in_sizes, int n_in,
                              void* d_out, int out_size, void* d_ws, size_t ws_size,
                              hipStream_t stream) {
  const float* hx = (const float*)d_in[0];
  const float* cx = (const float*)d_in[1];
  const float* Wm = (const float*)d_in[2];
  const float* Um = (const float*)d_in[3];
  const float* Lm = (const float*)d_in[4];
  float* out = (float*)d_out;

  // ws layout (needs ~59 MB):
  char* ws = (char*)d_ws;
  unsigned short* Ubf = (unsigned short*)(ws);               // 32 MB
  unsigned short* Wbf = (unsigned short*)(ws + 33554432);    // 24 MB
  unsigned short* Lbf = (unsigned short*)(ws + 58720256);    // 1 MB
  unsigned short* hbf = (unsigned short*)(ws + 59768832);    // 1 MB (2 bufs)
  float* c = (float*)(ws + 60817408);                        // 1 MB

  prep_kernel<<<2048, 256, 0, stream>>>(hx, cx, Wm, Um, Lm, Ubf, Wbf, Lbf, hbf, c);
  for (int w = 0; w < NWAVES; ++w) {
    wave_kernel<<<264, 256, 0, stream>>>(w, Ubf, Wbf, Lbf, hbf, c, out);
  }
}